// Round 4
// baseline (119.026 us; speedup 1.0000x reference)
//
#include <hip/hip_runtime.h>
#include <cmath>

#define WAVE 64
#define TPB  256      // 4 waves per workgroup
#define FTPB 1024

__device__ __forceinline__ float fastrcp(float x) { return __builtin_amdgcn_rcpf(x); }

__device__ __forceinline__ unsigned sortable_u32(float f) {
    unsigned b = __float_as_uint(f);
    return (b & 0x80000000u) ? ~b : (b | 0x80000000u);
}

// mask may arrive as u8 bool, i32, or f32 — probe byte pattern once.
__device__ __forceinline__ int mask_mode(const void* maskp) {
    const unsigned char* mb = (const unsigned char*)maskp;
    unsigned char b0 = mb[0], b1 = mb[1];
    if (b0 != 0 && b1 != 0) return 0;   // u8
    if (b0 != 0) return 1;              // i32
    return 2;                           // f32
}
__device__ __forceinline__ float mask_v(const void* maskp, int t, int mode) {
    if (mode == 0) return ((const unsigned char*)maskp)[t] ? 1.0f : 0.0f;
    if (mode == 1) return ((const int*)maskp)[t] ? 1.0f : 0.0f;
    return (((const float*)maskp)[t] != 0.0f) ? 1.0f : 0.0f;
}
__device__ __forceinline__ int midx(int m, int nsh, int N) {
    return (nsh >= 0) ? (m >> nsh) : (m / N);
}

// ---------------------------------------------------------------------------
// Single-pass tile kernel: each wave owns a 64x64 tile (64 rows x 64 cols).
// Lane = column: colsum accumulates lane-locally. Row-argmax via
// wave-synchronous LDS transpose in 8-row sub-tiles.
// Computes h = inter/uni + uni/areaC = giou + 1 (corrected in finalize).
// ---------------------------------------------------------------------------
__global__ __launch_bounds__(TPB) void pass_kernel(
        const float4* __restrict__ pred, const float4* __restrict__ tgt,
        const void* __restrict__ maskp, int M, int nsh, int N,
        unsigned long long* __restrict__ keypart, float* __restrict__ colpart) {
    __shared__ float rowst[64][8];        // x1 y1 x2 y2 area v pad pad
    __shared__ float tr[4][8][65];        // per-wave transpose buffer

    const int mode = mask_mode(maskp);
    const int CR   = M >> 8;              // 256-col ranges per row-group
    const int rg   = blockIdx.x / CR;
    const int cr   = blockIdx.x % CR;
    const int tid  = threadIdx.x;
    const int lane = tid & (WAVE - 1);
    const int warp = tid >> 6;
    const int i0   = rg * 64;

    // stage 64 target rows (shared by all 4 waves)
    if (tid < 64) {
        float4 t = tgt[i0 + tid];
        rowst[tid][0] = t.x; rowst[tid][1] = t.y;
        rowst[tid][2] = t.z; rowst[tid][3] = t.w;
        rowst[tid][4] = (t.z - t.x) * (t.w - t.y);
        rowst[tid][5] = mask_v(maskp, midx(i0 + tid, nsh, N), mode);
    }
    __syncthreads();

    // this lane's column (converted to xyxy, lane-resident for whole tile)
    const int c0 = (cr * 4 + warp) * 64;  // chunk base (64 cols per wave)
    const int c  = c0 + lane;
    float4 p = pred[c];
    float bx1 = p.x - 0.5f * p.z, by1 = p.y - 0.5f * p.w;
    float bx2 = p.x + 0.5f * p.z, by2 = p.y + 0.5f * p.w;
    float aB  = (bx2 - bx1) * (by2 - by1);
    float vc  = mask_v(maskp, midx(c, nsh, N), mode);
    bool  mv  = vc > 0.0f;

    float colacc = 0.0f;
    float bestv[8];
    int   besti[8];
#pragma unroll
    for (int s = 0; s < 8; ++s) { bestv[s] = -INFINITY; besti[s] = 0; }

    const int rbase  = lane & 7;          // row-in-subtile this lane reduces
    const int cslice = (lane >> 3) * 8;   // col slice (within chunk) it reduces

#pragma unroll
    for (int s = 0; s < 8; ++s) {         // 8 sub-tiles of 8 rows
#pragma unroll
        for (int r = 0; r < 8; ++r) {
            const int row = s * 8 + r;    // compile-time constant offsets
            float ax1 = rowst[row][0], ay1 = rowst[row][1];
            float ax2 = rowst[row][2], ay2 = rowst[row][3];
            float aA  = rowst[row][4], vi = rowst[row][5];
            float ltx = fmaxf(ax1, bx1), lty = fmaxf(ay1, by1);
            float rbx = fminf(ax2, bx2), rby = fminf(ay2, by2);
            float w = fmaxf(rbx - ltx, 0.0f), h = fmaxf(rby - lty, 0.0f);
            float inter = w * h;
            float uni = aA + aB - inter;
            float cx1 = fminf(ax1, bx1), cy1 = fminf(ay1, by1);
            float cx2 = fmaxf(ax2, bx2), cy2 = fmaxf(ay2, by2);
            float areaC = (cx2 - cx1) * (cy2 - cy1);  // >= 0 by construction
            float hval = fmaf(uni, fastrcp(areaC), inter * fastrcp(uni));
            colacc = fmaf(vi, hval, colacc);          // col-sum: lane-local
            tr[warp][r][lane] = mv ? hval : -INFINITY;
        }
        // wave-synchronous transpose read (same wave wrote; LDS is in-order)
#pragma unroll
        for (int j = 0; j < 8; ++j) {
            float val = tr[warp][rbase][cslice + j];
            int cidx = c0 + cslice + j;
            if (val > bestv[s]) { bestv[s] = val; besti[s] = cidx; } // strict >, ascending c
        }
    }

    // combine across the 8 lanes sharing rbase (disjoint col slices)
#pragma unroll
    for (int s = 0; s < 8; ++s) {
        unsigned long long key = ((unsigned long long)sortable_u32(bestv[s]) << 32)
                               | (unsigned)(~besti[s]);
#pragma unroll
        for (int off = 8; off <= 32; off <<= 1) {
            unsigned long long ok = __shfl_xor(key, off);
            key = (ok > key) ? ok : key;
        }
        if (lane < 8)
            keypart[(size_t)(cr * 4 + warp) * M + (i0 + s * 8 + lane)] = key;
    }
    colpart[(size_t)rg * M + c] = colacc;
}

// ---------------- combine partials -----------------------------------------
__global__ __launch_bounds__(TPB) void reduce_kernel(
        const unsigned long long* __restrict__ keypart,
        const float* __restrict__ colpart, int M, int P,
        int* __restrict__ idx, float* __restrict__ colsumh) {
    int m = blockIdx.x * blockDim.x + threadIdx.x;
    if (m >= M) return;
    unsigned long long k = keypart[m];
    for (int cc = 1; cc < P; ++cc) {
        unsigned long long kc = keypart[(size_t)cc * M + m];
        k = (kc > k) ? kc : k;
    }
    float s = colpart[m];
    for (int cc = 1; cc < P; ++cc) s += colpart[(size_t)cc * M + m];
    idx[m] = (int)(~(unsigned)k);
    colsumh[m] = s;
}

// ---------------- finalize: all scalar reductions, 1 block -----------------
__device__ __forceinline__ double wave_sum_d(double x) {
    for (int off = 32; off >= 1; off >>= 1) x += __shfl_xor(x, off);
    return x;
}

__global__ __launch_bounds__(FTPB) void finalize_kernel(
        const float4* __restrict__ pred, const float4* __restrict__ tgt,
        const void* __restrict__ maskp, int M, int nsh, int N,
        const int* __restrict__ idx, const float* __restrict__ colsumh,
        float* __restrict__ out) {
    __shared__ double red[4 * (FTPB / WAVE)];
    const int mode = mask_mode(maskp);
    const int tid = threadIdx.x;

    double sumV = 0.0, S2 = 0.0, S1h = 0.0, bbox = 0.0;
    for (int m = tid; m < M; m += FTPB) {
        float vi = mask_v(maskp, midx(m, nsh, N), mode);
        int   k  = idx[m];
        float vk = mask_v(maskp, midx(k, nsh, N), mode);
        sumV += (double)vi;
        S2   += (double)vk;
        S1h  += (double)vk * (double)colsumh[k];
        float4 p = pred[k];
        float sx1 = p.x - 0.5f * p.z, sy1 = p.y - 0.5f * p.w;
        float sx2 = p.x + 0.5f * p.z, sy2 = p.y + 0.5f * p.w;
        float4 t = tgt[m];
        bbox += (double)vi * (double)(fabsf(sx1 - t.x) + fabsf(sy1 - t.y) +
                                      fabsf(sx2 - t.z) + fabsf(sy2 - t.w));
    }
    sumV = wave_sum_d(sumV);
    S2   = wave_sum_d(S2);
    S1h  = wave_sum_d(S1h);
    bbox = wave_sum_d(bbox);
    int wid = tid >> 6, lane = tid & (WAVE - 1);
    const int NW = FTPB / WAVE;
    if (lane == 0) {
        red[wid] = sumV; red[NW + wid] = S2; red[2 * NW + wid] = S1h; red[3 * NW + wid] = bbox;
    }
    __syncthreads();
    if (tid == 0) {
        double a = 0, b = 0, c = 0, d = 0;
        for (int w = 0; w < NW; ++w) {
            a += red[w]; b += red[NW + w]; c += red[2 * NW + w]; d += red[3 * NW + w];
        }
        // colsum_g = colsum_h - sumV  =>  S1 = S1h - sumV*S2
        // loss_giou = 1 - S1/(sumV*S2) = 2 - S1h/(sumV*S2)
        out[0] = (float)(2.0 - c / (a * b));
        out[1] = (float)(d / (4.0 * a));
    }
}

// ---------------------------------------------------------------------------
extern "C" void kernel_launch(void* const* d_in, const int* in_sizes, int n_in,
                              void* d_out, int out_size, void* d_ws, size_t ws_size,
                              hipStream_t stream) {
    const float4* pred = (const float4*)d_in[0];
    const float4* tgt  = (const float4*)d_in[1];
    const void*   mask = d_in[2];

    int M = in_sizes[0] / 4;        // 4096 (B*T*N); must be multiple of 256
    int N = M / in_sizes[2];        // boxes per mask entry (8)
    int nsh = -1;
    for (int s = 0; s < 31; ++s) if ((1 << s) == N) { nsh = s; break; }

    int P = M / 64;                 // partial count (col-chunks / row-groups)

    char* ws = (char*)d_ws;
    unsigned long long* keypart = (unsigned long long*)ws; ws += (size_t)P * M * 8;
    float* colpart = (float*)ws;                           ws += (size_t)P * M * 4;
    int*   idx     = (int*)ws;                             ws += (size_t)M * 4;
    float* colsumh = (float*)ws;                           ws += (size_t)M * 4;
    float* out = (float*)d_out;

    int blocks = (M / 64) * (M / 256);   // row-groups x col-ranges
    pass_kernel<<<blocks, TPB, 0, stream>>>(pred, tgt, mask, M, nsh, N, keypart, colpart);

    reduce_kernel<<<(M + TPB - 1) / TPB, TPB, 0, stream>>>(keypart, colpart, M, P, idx, colsumh);

    finalize_kernel<<<1, FTPB, 0, stream>>>(pred, tgt, mask, M, nsh, N, idx, colsumh, out);
}

// Round 5
// 95.530 us; speedup vs baseline: 1.2460x; 1.2460x over previous
//
#include <hip/hip_runtime.h>
#include <cmath>

#define WAVE 64
#define TPB  256
#define FTPB 1024
#define KEY_INIT 0x007FFFFFFFFFFFFFull   // key(-inf, idx 0): all-masked row -> idx 0

__device__ __forceinline__ float fastrcp(float x) { return __builtin_amdgcn_rcpf(x); }

__device__ __forceinline__ unsigned sortable_u32(float f) {
    unsigned b = __float_as_uint(f);
    return (b & 0x80000000u) ? ~b : (b | 0x80000000u);
}

// mask may arrive as u8 bool, i32, or f32 — probe byte pattern.
__device__ __forceinline__ int mask_mode(const void* maskp) {
    const unsigned char* mb = (const unsigned char*)maskp;
    unsigned char b0 = mb[0], b1 = mb[1];
    if (b0 != 0 && b1 != 0) return 0;   // u8
    if (b0 != 0) return 1;              // i32
    return 2;                           // f32
}
__device__ __forceinline__ float mask_v(const void* maskp, int t, int mode) {
    if (mode == 0) return ((const unsigned char*)maskp)[t] ? 1.0f : 0.0f;
    if (mode == 1) return ((const int*)maskp)[t] ? 1.0f : 0.0f;
    return (((const float*)maskp)[t] != 0.0f) ? 1.0f : 0.0f;
}
__device__ __forceinline__ int midx(int m, int nsh, int N) {
    return (nsh >= 0) ? (m >> nsh) : (m / N);
}

// ---------------- prep: convert pred, areas, v; init atomic targets --------
__global__ __launch_bounds__(TPB) void prep_kernel(
        const float4* __restrict__ pred, const float4* __restrict__ tgt,
        const void* __restrict__ maskp, int M, int nsh, int N,
        float4* __restrict__ convS, float* __restrict__ areaS,
        float* __restrict__ areaT, float* __restrict__ vv,
        unsigned long long* __restrict__ rowkey, float* __restrict__ colsumG) {
    int m = blockIdx.x * blockDim.x + threadIdx.x;
    if (m >= M) return;
    float4 p = pred[m];
    float x1 = p.x - 0.5f * p.z, y1 = p.y - 0.5f * p.w;
    float x2 = p.x + 0.5f * p.z, y2 = p.y + 0.5f * p.w;
    convS[m] = make_float4(x1, y1, x2, y2);
    areaS[m] = (x2 - x1) * (y2 - y1);
    float4 t = tgt[m];
    areaT[m] = (t.z - t.x) * (t.w - t.y);
    vv[m] = mask_v(maskp, midx(m, nsh, N), mask_mode(maskp));
    rowkey[m] = KEY_INIT;
    colsumG[m] = 0.0f;
}

// ---------------- single-pass tile: lane=row, wave-uniform column ----------
__global__ __launch_bounds__(TPB) void pass_kernel(
        const float4* __restrict__ tgt, const float* __restrict__ areaT,
        const float4* __restrict__ convS, const float* __restrict__ areaS,
        const float* __restrict__ vv, int M,
        unsigned long long* __restrict__ rowkey, float* __restrict__ colsumG) {
    const int CC   = M >> 6;                        // column chunks
    const int wid  = blockIdx.x * (TPB / WAVE) + (threadIdx.x >> 6);
    const int lane = threadIdx.x & (WAVE - 1);
    const int rb   = wid / CC;
    const int cc   = wid % CC;
    const int r    = rb * 64 + lane;
    const int c0   = cc * 64;

    // lane-resident row (target) box
    float4 a  = tgt[r];
    float  aA = areaT[r];
    float  vi = vv[r];

    // column mask for this chunk, one bit per column
    float vc = vv[c0 + lane];
    unsigned long long cm = __ballot(vc > 0.0f);

    float best = -INFINITY;
    int   bidx = 0;
    float csum = 0.0f;

    const float4* __restrict__ bcol = convS + c0;   // uniform-indexed -> s_load
    const float*  __restrict__ bare = areaS + c0;

#pragma unroll 8
    for (int j = 0; j < 64; ++j) {
        float4 b  = bcol[j];
        float  aB = bare[j];
        // GIoU (h = giou + 1 form; exact correction in finalize)
        float ltx = fmaxf(a.x, b.x), lty = fmaxf(a.y, b.y);
        float rbx = fminf(a.z, b.z), rby = fminf(a.w, b.w);
        float w = fmaxf(rbx - ltx, 0.0f), h = fmaxf(rby - lty, 0.0f);
        float inter = w * h;
        float uni = aA + aB - inter;
        float cx1 = fminf(a.x, b.x), cy1 = fminf(a.y, b.y);
        float cx2 = fmaxf(a.z, b.z), cy2 = fmaxf(a.w, b.w);
        float areaC = (cx2 - cx1) * (cy2 - cy1);    // >= 0 by construction
        float hval = fmaf(uni, fastrcp(areaC), inter * fastrcp(uni));

        // column-sum partial: butterfly over the 64 rows (register-only)
        float t = vi * hval;
        for (int off = 1; off <= 32; off <<= 1) t += __shfl_xor(t, off);
        csum = (lane == j) ? t : csum;              // lane j keeps column j's sum

        // row-argmax: skip masked columns via uniform (scalar) branch
        if ((cm >> j) & 1ull) {
            if (hval > best) { best = hval; bidx = c0 + j; }  // strict >, ascending j
        }
    }

    unsigned long long key = ((unsigned long long)sortable_u32(best) << 32)
                           | (unsigned)(~bidx);
    atomicMax(&rowkey[r], key);                     // exact first-max, order-free
    atomicAdd(&colsumG[c0 + lane], csum);           // coalesced, 64-way contention
}

// ---------------- finalize: all scalar reductions, 1 block -----------------
__device__ __forceinline__ double wave_sum_d(double x) {
    for (int off = 32; off >= 1; off >>= 1) x += __shfl_xor(x, off);
    return x;
}

__global__ __launch_bounds__(FTPB) void finalize_kernel(
        const float4* __restrict__ convS, const float4* __restrict__ tgt,
        const float* __restrict__ vv, const unsigned long long* __restrict__ rowkey,
        const float* __restrict__ colsumG, int M, float* __restrict__ out) {
    __shared__ double red[4 * (FTPB / WAVE)];
    const int tid = threadIdx.x;

    double sumV = 0.0, S2 = 0.0, S1h = 0.0, bbox = 0.0;
    for (int m = tid; m < M; m += FTPB) {
        float vi = vv[m];
        int   k  = (int)(~(unsigned)rowkey[m]);
        float vk = vv[k];
        sumV += (double)vi;
        S2   += (double)vk;
        S1h  += (double)vk * (double)colsumG[k];
        float4 s = convS[k];
        float4 t = tgt[m];
        bbox += (double)vi * (double)(fabsf(s.x - t.x) + fabsf(s.y - t.y) +
                                      fabsf(s.z - t.z) + fabsf(s.w - t.w));
    }
    sumV = wave_sum_d(sumV);
    S2   = wave_sum_d(S2);
    S1h  = wave_sum_d(S1h);
    bbox = wave_sum_d(bbox);
    int wid = tid >> 6, lane = tid & (WAVE - 1);
    const int NW = FTPB / WAVE;
    if (lane == 0) {
        red[wid] = sumV; red[NW + wid] = S2; red[2 * NW + wid] = S1h; red[3 * NW + wid] = bbox;
    }
    __syncthreads();
    if (tid == 0) {
        double a = 0, b = 0, c = 0, d = 0;
        for (int w = 0; w < NW; ++w) {
            a += red[w]; b += red[NW + w]; c += red[2 * NW + w]; d += red[3 * NW + w];
        }
        // colsum_g = colsum_h - sumV  =>  loss_giou = 2 - S1h/(sumV*S2)
        out[0] = (float)(2.0 - c / (a * b));
        out[1] = (float)(d / (4.0 * a));
    }
}

// ---------------------------------------------------------------------------
extern "C" void kernel_launch(void* const* d_in, const int* in_sizes, int n_in,
                              void* d_out, int out_size, void* d_ws, size_t ws_size,
                              hipStream_t stream) {
    const float4* pred = (const float4*)d_in[0];
    const float4* tgt  = (const float4*)d_in[1];
    const void*   mask = d_in[2];

    int M = in_sizes[0] / 4;        // 4096 (B*T*N); multiple of 64
    int N = M / in_sizes[2];        // boxes per mask entry (8)
    int nsh = -1;
    for (int s = 0; s < 31; ++s) if ((1 << s) == N) { nsh = s; break; }

    char* ws = (char*)d_ws;
    float4* convS   = (float4*)ws;             ws += (size_t)M * 16;
    float*  areaS   = (float*)ws;              ws += (size_t)M * 4;
    float*  areaT   = (float*)ws;              ws += (size_t)M * 4;
    float*  vv      = (float*)ws;              ws += (size_t)M * 4;
    unsigned long long* rowkey = (unsigned long long*)ws; ws += (size_t)M * 8;
    float*  colsumG = (float*)ws;              ws += (size_t)M * 4;
    float*  out = (float*)d_out;

    prep_kernel<<<(M + TPB - 1) / TPB, TPB, 0, stream>>>(
        pred, tgt, mask, M, nsh, N, convS, areaS, areaT, vv, rowkey, colsumG);

    int waves  = (M / 64) * (M / 64);           // 4096
    int blocks = waves / (TPB / WAVE);          // 1024
    pass_kernel<<<blocks, TPB, 0, stream>>>(
        tgt, areaT, convS, areaS, vv, M, rowkey, colsumG);

    finalize_kernel<<<1, FTPB, 0, stream>>>(convS, tgt, vv, rowkey, colsumG, M, out);
}